// Round 1
// baseline (1509.739 us; speedup 1.0000x reference)
//
#include <hip/hip_runtime.h>
#include <math.h>

// VocabProjector: per (b,t) row of 128000 fp32 teacher logits:
//   top-256 (softmax-monotone => top-k on raw logits, ties -> lowest index),
//   p_i = exp((l_i - m)/4), out[map[i]] += p_i / sum(p), rest zeros.
// Full-vocab softmax denom cancels in the renormalization -> single pass.
//
// Fast path: static filter (logit > 2.0) pushes candidates to LDS
// (input is N(0,1): ~2912 cand/row; <256 or >4096 is a >20-sigma event),
// then exact 4-round byte radix select on ordered fp32 bits in LDS.
// Fallback (never taken for the bench input): radix select re-scanning global.

#define VT 128000
#define VS 32000
#define TOPK 256
#define NT 256
#define CAP 4096
#define EQCAP 1024
#define INV_TEMP 0.25f
#define THRESH 2.0f

__device__ __forceinline__ unsigned int f2o(float f) {
  unsigned int u = __float_as_uint(f);
  // monotone map: float total order -> unsigned order
  return u ^ ((unsigned int)((int)u >> 31) | 0x80000000u);
}
__device__ __forceinline__ float o2f(unsigned int ou) {
  unsigned int u = (ou & 0x80000000u) ? (ou ^ 0x80000000u) : ~ou;
  return __uint_as_float(u);
}

__global__ __launch_bounds__(NT) void vocab_proj(const float* __restrict__ logits,
                                                 const int* __restrict__ mapping,
                                                 float* __restrict__ out) {
  const int row = blockIdx.x;
  const int tid = threadIdx.x;
  const float* rl = logits + (size_t)row * VT;
  float* ro = out + (size_t)row * VS;

  __shared__ unsigned int cand_val[CAP];  // ordered fp32 bits
  __shared__ int cand_idx[CAP];
  __shared__ unsigned int hist[256];
  __shared__ unsigned int sel_val[TOPK];
  __shared__ int sel_idx[TOPK];
  __shared__ int eq_idx[EQCAP];
  __shared__ unsigned int s_cnt, s_selcnt, s_eqcnt, s_prefix, s_kneed;
  __shared__ float s_max, s_sum;
  __shared__ float s_red[NT / 64];

  if (tid == 0) s_cnt = 0u;
  __syncthreads();

  // ---- zero this block's output row (d_out is poisoned each launch) ----
  float4 z4 = make_float4(0.f, 0.f, 0.f, 0.f);
  float4* ro4 = (float4*)ro;
  for (int i = tid; i < VS / 4; i += NT) ro4[i] = z4;

  // ---- single streaming pass: collect candidates above static threshold ----
  const float4* rl4 = (const float4*)rl;
  for (int i = tid; i < VT / 4; i += NT) {
    float4 v = rl4[i];
    int base = i * 4;
    float vv[4] = {v.x, v.y, v.z, v.w};
#pragma unroll
    for (int c = 0; c < 4; ++c) {
      if (vv[c] > THRESH) {
        unsigned int p = atomicAdd(&s_cnt, 1u);
        if (p < CAP) { cand_val[p] = f2o(vv[c]); cand_idx[p] = base + c; }
      }
    }
  }
  __syncthreads();
  const unsigned int n = s_cnt;
  const bool fb = (n < TOPK) || (n > CAP);  // fallback: rescan global

  // ---- exact radix select: ordered bits of the rank-TOPK value (desc) ----
  if (tid == 0) { s_prefix = 0u; s_kneed = TOPK; }
  __syncthreads();
  for (int shift = 24; shift >= 0; shift -= 8) {
    const unsigned int pmask = (shift == 24) ? 0u : (0xFFFFFFFFu << (shift + 8));
    const unsigned int prefix = s_prefix;
    hist[tid] = 0u;
    __syncthreads();
    if (!fb) {
      for (unsigned int i = tid; i < n; i += NT) {
        unsigned int v = cand_val[i];
        if ((v & pmask) == prefix) atomicAdd(&hist[(v >> shift) & 255u], 1u);
      }
    } else {
      for (int i = tid; i < VT; i += NT) {
        unsigned int v = f2o(rl[i]);
        if ((v & pmask) == prefix) atomicAdd(&hist[(v >> shift) & 255u], 1u);
      }
    }
    __syncthreads();
    if (tid == 0) {
      unsigned int kn = s_kneed, cum = 0u;
      int b = 255;
      for (; b > 0; --b) {
        unsigned int h = hist[b];
        if (cum + h >= kn) break;
        cum += h;
      }
      s_prefix = prefix | ((unsigned int)b << shift);
      s_kneed = kn - cum;  // how many to take from values == threshold
    }
    __syncthreads();
  }
  const unsigned int Vord = s_prefix;
  const unsigned int kneed = s_kneed;

  // ---- collect: strictly-greater are in; ties filled by smallest index ----
  if (tid == 0) { s_selcnt = 0u; s_eqcnt = 0u; }
  __syncthreads();
  if (!fb) {
    for (unsigned int i = tid; i < n; i += NT) {
      unsigned int v = cand_val[i];
      if (v > Vord) {
        unsigned int p = atomicAdd(&s_selcnt, 1u);
        sel_val[p] = v; sel_idx[p] = cand_idx[i];
      } else if (v == Vord) {
        unsigned int p = atomicAdd(&s_eqcnt, 1u);
        if (p < EQCAP) eq_idx[p] = cand_idx[i];
      }
    }
  } else {
    for (int i = tid; i < VT; i += NT) {
      unsigned int v = f2o(rl[i]);
      if (v > Vord) {
        unsigned int p = atomicAdd(&s_selcnt, 1u);
        if (p < TOPK) { sel_val[p] = v; sel_idx[p] = i; }
      } else if (v == Vord) {
        unsigned int p = atomicAdd(&s_eqcnt, 1u);
        if (p < EQCAP) eq_idx[p] = i;
      }
    }
  }
  __syncthreads();
  const unsigned int G = s_selcnt;  // == TOPK - kneed

  if (tid == 0) {
    // ascending index sort of tie candidates (almost always e <= 3)
    int e = (int)(s_eqcnt < (unsigned int)EQCAP ? s_eqcnt : (unsigned int)EQCAP);
    for (int a = 1; a < e; ++a) {
      int key = eq_idx[a]; int b2 = a - 1;
      while (b2 >= 0 && eq_idx[b2] > key) { eq_idx[b2 + 1] = eq_idx[b2]; --b2; }
      eq_idx[b2 + 1] = key;
    }
  }
  __syncthreads();
  if (tid < (int)kneed) {
    sel_val[G + tid] = Vord;
    sel_idx[G + tid] = eq_idx[tid];
  }
  __syncthreads();

  // ---- epilogue: normalized exp over exactly TOPK==NT selected ----
  if (tid == 0) {
    unsigned int mx = 0u;
    for (int i = 0; i < TOPK; ++i) mx = (sel_val[i] > mx) ? sel_val[i] : mx;
    s_max = o2f(mx);
  }
  __syncthreads();
  const float m = s_max;
  const float f = o2f(sel_val[tid]);
  const float p0 = expf((f - m) * INV_TEMP);

  float p = p0;
#pragma unroll
  for (int o = 32; o > 0; o >>= 1) p += __shfl_down(p, o, 64);
  if ((tid & 63) == 0) s_red[tid >> 6] = p;
  __syncthreads();
  if (tid == 0) s_sum = s_red[0] + s_red[1] + s_red[2] + s_red[3];
  __syncthreads();

  int sid = mapping[sel_idx[tid]];
  sid = sid < 0 ? 0 : (sid >= VS ? VS - 1 : sid);
  atomicAdd(&ro[sid], p0 / s_sum);
}

extern "C" void kernel_launch(void* const* d_in, const int* in_sizes, int n_in,
                              void* d_out, int out_size, void* d_ws, size_t ws_size,
                              hipStream_t stream) {
  const float* logits = (const float*)d_in[0];
  const int* mapping = (const int*)d_in[1];
  float* out = (float*)d_out;
  const int rows = in_sizes[0] / VT;  // B*T = 2048
  vocab_proj<<<dim3(rows), dim3(NT), 0, stream>>>(logits, mapping, out);
}